// Round 12
// baseline (59.124 us; speedup 1.0000x reference)
//
#include <hip/hip_runtime.h>
#include <hip/hip_bf16.h>

// x[4096,2048] f32, w[2048,2048] f32, bias[2048] f32, indices = permutation of
// K axis applied to BOTH operands -> cancels out of the einsum; unused.
#define M_DIM 4096
#define N_DIM 2048
#define K_DIM 2048

// R11 geometry (128x128, 4 waves, 2 blocks/CU, BK=32 triple-buffer, packed-
// line swizzle, 2D XCD map) + LIVENESS-PINNED phase-ahead register sets:
// READ_SET(next) issues before MFMA(cur); an empty asm "use" of the next-set
// AFTER the MFMA cluster forces (a) both sets live -> no register merge,
// (b) the lgkm wait for the reads to land after the MFMAs -> latency hidden.
#define BM 128
#define BN 128
#define BK 32
#define NT (K_DIM / BK)      // 64 K-tiles
#define A_TILE (BM * BK)     // 4096 elems = 8 KiB
#define B_TILE (BN * BK)     // 4096 elems = 8 KiB

typedef __bf16 bf16x8 __attribute__((ext_vector_type(8)));
typedef float f32x4 __attribute__((ext_vector_type(4)));
typedef unsigned short u16x8 __attribute__((ext_vector_type(8)));

__device__ __forceinline__ unsigned short f32_to_bf16_rne(float f) {
  unsigned int u = __float_as_uint(f);
  u += 0x7fffu + ((u >> 16) & 1u);
  return (unsigned short)(u >> 16);
}

// ---- merged f32 -> bf16 conversion (row-major, verified) ----
__global__ __launch_bounds__(256) void cvt_both(
    const float* __restrict__ x, const float* __restrict__ w,
    unsigned short* __restrict__ out, int xn8, int totn8) {
  int i = blockIdx.x * 256 + threadIdx.x;
  if (i >= totn8) return;
  const float* src = (i < xn8) ? (x + (size_t)i * 8)
                               : (w + (size_t)(i - xn8) * 8);
  f32x4 a = reinterpret_cast<const f32x4*>(src)[0];
  f32x4 b = reinterpret_cast<const f32x4*>(src)[1];
  u16x8 o;
  o[0] = f32_to_bf16_rne(a[0]); o[1] = f32_to_bf16_rne(a[1]);
  o[2] = f32_to_bf16_rne(a[2]); o[3] = f32_to_bf16_rne(a[3]);
  o[4] = f32_to_bf16_rne(b[0]); o[5] = f32_to_bf16_rne(b[1]);
  o[6] = f32_to_bf16_rne(b[2]); o[7] = f32_to_bf16_rne(b[3]);
  reinterpret_cast<u16x8*>(out)[i] = o;
}

__device__ __forceinline__ void gload_lds16(const unsigned short* g, unsigned short* l) {
  __builtin_amdgcn_global_load_lds(
      (const __attribute__((address_space(1))) unsigned int*)g,
      (__attribute__((address_space(3))) unsigned int*)l, 16, 0, 0);
}

#define LD8(p) (*reinterpret_cast<const bf16x8*>(p))
#define VMWAIT_(n) asm volatile("s_waitcnt vmcnt(" #n ")" ::: "memory")
#define VMWAIT(n) VMWAIT_(n)
#define SBAR() __builtin_amdgcn_s_barrier()
#define SCHED() __builtin_amdgcn_sched_barrier(0)

__global__ __launch_bounds__(256, 2) void gemm_pin(
    const unsigned short* __restrict__ A,   // [M][K] bf16 bits
    const unsigned short* __restrict__ B,   // [N][K] bf16 bits
    const float* __restrict__ bias,         // [N]
    float* __restrict__ C) {                // [M][N] f32
  __shared__ unsigned short As[3 * A_TILE]; // 24 KiB
  __shared__ unsigned short Bs[3 * B_TILE]; // 24 KiB

  const int tid  = threadIdx.x;   // 0..255
  const int lane = tid & 63;
  const int wave = tid >> 6;      // 0..3
  const int wr   = wave >> 1;     // 0..1 (M)
  const int wc   = wave & 1;      // 0..1 (N)

  // 2D XCD swizzle (R9/R11-verified: FETCH halved).
  const int orig = blockIdx.x;    // 0..511
  const int xcd  = orig & 7;
  const int idx  = orig >> 3;     // 0..63
  const int bm   = (xcd & 3) * 8 + (idx & 7);   // 0..31
  const int bn   = (xcd >> 2) * 8 + (idx >> 3); // 0..15

  // ---- staging source (inverse-permuted global addresses; rule 21) ----
  const int lid  = tid >> 3;                    // line within issue
  const int uu   = (tid & 7) ^ (lid & 7);
  const int grow = 2 * lid + (uu >> 2);         // row within 64-row group
  const int kc   = (uu & 3) * 8;
  const unsigned short* Ag[2];
  const unsigned short* Bg[2];
#pragma unroll
  for (int j = 0; j < 2; ++j) {
    Ag[j] = A + (size_t)(bm * BM + j * 64 + grow) * K_DIM + kc;
    Bg[j] = B + (size_t)(bn * BN + j * 64 + grow) * K_DIM + kc;
  }

#define STAGE(bufLit, k0) do { \
    unsigned short* _da = &As[(bufLit) * A_TILE + tid * 8]; \
    unsigned short* _db = &Bs[(bufLit) * B_TILE + tid * 8]; \
    gload_lds16(Ag[0] + (k0), _da); \
    gload_lds16(Ag[1] + (k0), _da + 2048); \
    gload_lds16(Bg[0] + (k0), _db); \
    gload_lds16(Bg[1] + (k0), _db + 2048); \
  } while (0)

  // ---- ds_read offsets: packed-line layout (R10/R11-verified, 0 conflicts)
  const int fr = lane & 15;
  const int qq = lane >> 4;
  int aoff[4], boff[4];
#pragma unroll
  for (int mi = 0; mi < 4; ++mi) {
    const int R = wr * 64 + mi * 16 + fr;
    aoff[mi] = (R >> 1) * 64 + ((((R & 1) * 4 + qq) ^ ((R >> 1) & 7)) * 8);
  }
#pragma unroll
  for (int ni = 0; ni < 4; ++ni) {
    const int R = wc * 64 + ni * 16 + fr;
    boff[ni] = (R >> 1) * 64 + ((((R & 1) * 4 + qq) ^ ((R >> 1) & 7)) * 8);
  }

  const f32x4 z = {0.f, 0.f, 0.f, 0.f};
  f32x4 acc[4][4];
#pragma unroll
  for (int i = 0; i < 4; ++i)
#pragma unroll
    for (int j = 0; j < 4; ++j) acc[i][j] = z;

  bf16x8 Xa[4], Xb[4], Ya[4], Yb[4];

#define READ_SET(Sa, Sb, bufLit) do { \
    const unsigned short* _a = &As[(bufLit) * A_TILE]; \
    const unsigned short* _b = &Bs[(bufLit) * B_TILE]; \
    Sb[0] = LD8(_b + boff[0]); Sb[1] = LD8(_b + boff[1]); \
    Sb[2] = LD8(_b + boff[2]); Sb[3] = LD8(_b + boff[3]); \
    Sa[0] = LD8(_a + aoff[0]); Sa[1] = LD8(_a + aoff[1]); \
    Sa[2] = LD8(_a + aoff[2]); Sa[3] = LD8(_a + aoff[3]); \
  } while (0)

  // Liveness pin: forces Sa/Sb materialized HERE (compiler emits the lgkm
  // wait for their ds_reads at this point, after the MFMA cluster below).
#define PIN(Sa, Sb) asm volatile("" :: \
    "v"(Sa[0]), "v"(Sa[1]), "v"(Sa[2]), "v"(Sa[3]), \
    "v"(Sb[0]), "v"(Sb[1]), "v"(Sb[2]), "v"(Sb[3]))

#define MFMA_SET(Sa, Sb) do { \
    __builtin_amdgcn_s_setprio(1); \
    _Pragma("unroll") \
    for (int mi = 0; mi < 4; ++mi) { \
      acc[mi][0] = __builtin_amdgcn_mfma_f32_16x16x32_bf16(Sa[mi], Sb[0], acc[mi][0], 0, 0, 0); \
      acc[mi][1] = __builtin_amdgcn_mfma_f32_16x16x32_bf16(Sa[mi], Sb[1], acc[mi][1], 0, 0, 0); \
      acc[mi][2] = __builtin_amdgcn_mfma_f32_16x16x32_bf16(Sa[mi], Sb[2], acc[mi][2], 0, 0, 0); \
      acc[mi][3] = __builtin_amdgcn_mfma_f32_16x16x32_bf16(Sa[mi], Sb[3], acc[mi][3], 0, 0, 0); \
    } \
    __builtin_amdgcn_s_setprio(0); \
  } while (0)

  // Tile t: X holds tile t (read during t-1, waited at t-1's PIN).
  //  1. STAGE(t+2)                    (vmem, outstanding 8)
  //  2. VMWAIT(4); SBAR              (stage(t+1) visible to all waves)
  //  3. READ_SET(next <- buf[t+1])   (12 ds_reads in flight)
  //  4. [sched wall] MFMA_SET(cur)   (no wait: cur ready since last PIN)
  //  5. [sched wall] PIN(next)       (lgkm wait lands HERE, under MFMAs)
  //  6. SBAR                         (all waves' reads of buf[t] drained
  //                                   before anyone stages into it at t+1)
#define TILE(stgB, rdB, CURa, CURb, NXTa, NXTb, k0) do { \
    STAGE(stgB, k0); \
    VMWAIT(4); \
    SBAR(); \
    SCHED(); \
    READ_SET(NXTa, NXTb, rdB); \
    SCHED(); \
    MFMA_SET(CURa, CURb); \
    SCHED(); \
    PIN(NXTa, NXTb); \
    SBAR(); \
  } while (0)

  // prologue: stage tiles 0,1; wait tile 0; read+pin tile-0 regs into X.
  STAGE(0, 0);
  STAGE(1, BK);
  VMWAIT(4);
  SBAR();
  SCHED();
  READ_SET(Xa, Xb, 0);
  PIN(Xa, Xb);

  // main loop: tiles 0..59 (staging 2..61), 6-tile body for literal bufs.
  // even t: MFMA X, read Y; odd t: MFMA Y, read X.
#pragma unroll 1
  for (int s = 0; s < 10; ++s) {
    const int kb = (6 * s + 2) * BK;
    TILE(2, 1, Xa, Xb, Ya, Yb, kb);            // t=6s+0
    TILE(0, 2, Ya, Yb, Xa, Xb, kb + BK);       // t=6s+1
    TILE(1, 0, Xa, Xb, Ya, Yb, kb + 2 * BK);   // t=6s+2
    TILE(2, 1, Ya, Yb, Xa, Xb, kb + 3 * BK);   // t=6s+3
    TILE(0, 2, Xa, Xb, Ya, Yb, kb + 4 * BK);   // t=6s+4
    TILE(1, 0, Ya, Yb, Xa, Xb, kb + 5 * BK);   // t=6s+5
  }

  // tail: t=60 stages 62 (buf2), t=61 stages 63 (buf0).
  TILE(2, 1, Xa, Xb, Ya, Yb, 62 * BK);         // t=60
  TILE(0, 2, Ya, Yb, Xa, Xb, 63 * BK);         // t=61
  // t=62: no staging; drain stage(63); read+pin tile-63 into Y; MFMA X.
  VMWAIT(0);
  SBAR();
  SCHED();
  READ_SET(Ya, Yb, 0);
  SCHED();
  MFMA_SET(Xa, Xb);
  SCHED();
  PIN(Ya, Yb);
  MFMA_SET(Ya, Yb);                            // t=63

  // ---- epilogue: C/D layout col = lane&15, row = (lane>>4)*4 + r ----
  const int orow0 = bm * BM + wr * 64 + qq * 4;
  const int ocol0 = bn * BN + wc * 64 + fr;
#pragma unroll
  for (int ni = 0; ni < 4; ++ni) {
    const int col = ocol0 + ni * 16;
    const float bvv = bias[col];
#pragma unroll
    for (int mi = 0; mi < 4; ++mi) {
      const int row = orow0 + mi * 16;
#pragma unroll
      for (int r = 0; r < 4; ++r)
        C[(size_t)(row + r) * N_DIM + col] = acc[mi][ni][r] + bvv;
    }
  }
#undef TILE
#undef MFMA_SET
#undef PIN
#undef READ_SET
#undef STAGE
}

// ---- safety fallback ----
__global__ __launch_bounds__(256) void gemm_f32_naive(
    const float* __restrict__ X, const float* __restrict__ W,
    const float* __restrict__ bias, float* __restrict__ C) {
  int o = blockIdx.x * 256 + threadIdx.x;
  if (o >= M_DIM * N_DIM) return;
  int m = o / N_DIM, n = o % N_DIM;
  const float* xr = X + (size_t)m * K_DIM;
  const float* wr = W + (size_t)n * K_DIM;
  float s = 0.f;
  for (int k = 0; k < K_DIM; ++k) s += xr[k] * wr[k];
  C[o] = s + bias[n];
}

extern "C" void kernel_launch(void* const* d_in, const int* in_sizes, int n_in,
                              void* d_out, int out_size, void* d_ws, size_t ws_size,
                              hipStream_t stream) {
  const float* x    = (const float*)d_in[0];
  const float* w    = (const float*)d_in[1];
  const float* bias = (const float*)d_in[2];
  float* out = (float*)d_out;

  const size_t x_elems = (size_t)M_DIM * K_DIM;
  const size_t w_elems = (size_t)N_DIM * K_DIM;
  const size_t need = (x_elems + w_elems) * sizeof(unsigned short);

  if (ws_size < need) {
    gemm_f32_naive<<<(M_DIM * N_DIM + 255) / 256, 256, 0, stream>>>(x, w, bias, out);
    return;
  }

  unsigned short* xb = (unsigned short*)d_ws;
  unsigned short* wb = xb + x_elems;

  const int xn8 = (int)(x_elems / 8);
  const int totn8 = (int)((x_elems + w_elems) / 8);
  cvt_both<<<(totn8 + 255) / 256, 256, 0, stream>>>(x, w, xb, xn8, totn8);

  // (2048/128) x (4096/128) = 512 blocks = 2/CU.
  gemm_pin<<<512, 256, 0, stream>>>(xb, wb, bias, out);
}

// Round 13
// 56.749 us; speedup vs baseline: 1.0418x; 1.0418x over previous
//
#include <hip/hip_runtime.h>
#include <hip/hip_bf16.h>

// x[4096,2048] f32, w[2048,2048] f32, bias[2048] f32, indices = permutation of
// K axis applied to BOTH operands -> cancels out of the einsum; unused.
#define M_DIM 4096
#define N_DIM 2048
#define K_DIM 2048

// R11 geometry (128x128, 4 waves, 2 blocks/CU, BK=32, triple buffer, packed-
// line swizzle, 2D XCD map) + OPAQUE inline-asm ds_read fragment loads:
// the compiler cannot merge/sink asm outputs, so the two fragment sets are
// genuinely live and the lgkmcnt(0) wait sits AFTER the MFMA cluster.
#define BM 128
#define BN 128
#define BK 32
#define NT (K_DIM / BK)      // 64 K-tiles
#define BUF_EL 8192          // elems per buffer: A 4096 + B 4096 (16 KiB)

typedef __bf16 bf16x8 __attribute__((ext_vector_type(8)));
typedef float f32x4 __attribute__((ext_vector_type(4)));
typedef int   i32x4 __attribute__((ext_vector_type(4)));
typedef unsigned short u16x8 __attribute__((ext_vector_type(8)));

__device__ __forceinline__ unsigned short f32_to_bf16_rne(float f) {
  unsigned int u = __float_as_uint(f);
  u += 0x7fffu + ((u >> 16) & 1u);
  return (unsigned short)(u >> 16);
}

// ---- merged f32 -> bf16 conversion (row-major, verified) ----
__global__ __launch_bounds__(256) void cvt_both(
    const float* __restrict__ x, const float* __restrict__ w,
    unsigned short* __restrict__ out, int xn8, int totn8) {
  int i = blockIdx.x * 256 + threadIdx.x;
  if (i >= totn8) return;
  const float* src = (i < xn8) ? (x + (size_t)i * 8)
                               : (w + (size_t)(i - xn8) * 8);
  f32x4 a = reinterpret_cast<const f32x4*>(src)[0];
  f32x4 b = reinterpret_cast<const f32x4*>(src)[1];
  u16x8 o;
  o[0] = f32_to_bf16_rne(a[0]); o[1] = f32_to_bf16_rne(a[1]);
  o[2] = f32_to_bf16_rne(a[2]); o[3] = f32_to_bf16_rne(a[3]);
  o[4] = f32_to_bf16_rne(b[0]); o[5] = f32_to_bf16_rne(b[1]);
  o[6] = f32_to_bf16_rne(b[2]); o[7] = f32_to_bf16_rne(b[3]);
  reinterpret_cast<u16x8*>(out)[i] = o;
}

__device__ __forceinline__ void gload_lds16(const unsigned short* g, unsigned short* l) {
  __builtin_amdgcn_global_load_lds(
      (const __attribute__((address_space(1))) unsigned int*)g,
      (__attribute__((address_space(3))) unsigned int*)l, 16, 0, 0);
}

#define VMWAIT_(n) asm volatile("s_waitcnt vmcnt(" #n ")" ::: "memory")
#define VMWAIT(n) VMWAIT_(n)
#define LGKM0() do { \
    asm volatile("s_waitcnt lgkmcnt(0)" ::: "memory"); \
    __builtin_amdgcn_sched_barrier(0); \
  } while (0)
#define SBAR() __builtin_amdgcn_s_barrier()
#define SCHED() __builtin_amdgcn_sched_barrier(0)

// Opaque LDS read: buffer selected by 16-bit offset: immediate (literal).
#define DSREAD(dst, addr, OFS) \
  asm volatile("ds_read_b128 %0, %1 offset:" OFS : "=v"(dst) : "v"(addr))

#define BCAST(v) __builtin_bit_cast(bf16x8, v)

__global__ __launch_bounds__(256, 2) void gemm_asm(
    const unsigned short* __restrict__ A,   // [M][K] bf16 bits
    const unsigned short* __restrict__ B,   // [N][K] bf16 bits
    const float* __restrict__ bias,         // [N]
    float* __restrict__ C) {                // [M][N] f32
  __shared__ unsigned short L[3 * BUF_EL];  // 48 KiB: per buf {A 8K | B 8K}

  const int tid  = threadIdx.x;   // 0..255
  const int lane = tid & 63;
  const int wave = tid >> 6;      // 0..3
  const int wr   = wave >> 1;     // 0..1 (M)
  const int wc   = wave & 1;      // 0..1 (N)

  // 2D XCD swizzle (verified: FETCH halved).
  const int orig = blockIdx.x;    // 0..511
  const int xcd  = orig & 7;
  const int idx  = orig >> 3;     // 0..63
  const int bm   = (xcd & 3) * 8 + (idx & 7);   // 0..31
  const int bn   = (xcd >> 2) * 8 + (idx >> 3); // 0..15

  // ---- staging source (inverse-permuted global addresses; rule 21) ----
  const int lid  = tid >> 3;
  const int uu   = (tid & 7) ^ (lid & 7);
  const int grow = 2 * lid + (uu >> 2);
  const int kc   = (uu & 3) * 8;
  const unsigned short* Ag[2];
  const unsigned short* Bg[2];
#pragma unroll
  for (int j = 0; j < 2; ++j) {
    Ag[j] = A + (size_t)(bm * BM + j * 64 + grow) * K_DIM + kc;
    Bg[j] = B + (size_t)(bn * BN + j * 64 + grow) * K_DIM + kc;
  }

  // dest within buf: A at elem 0, B at elem 4096. Linear (rule 21).
#define STAGE(bufLit, k0) do { \
    unsigned short* _da = &L[(bufLit) * BUF_EL + tid * 8]; \
    unsigned short* _db = &L[(bufLit) * BUF_EL + 4096 + tid * 8]; \
    gload_lds16(Ag[0] + (k0), _da); \
    gload_lds16(Ag[1] + (k0), _da + 2048); \
    gload_lds16(Bg[0] + (k0), _db); \
    gload_lds16(Bg[1] + (k0), _db + 2048); \
  } while (0)

  // ---- ds_read addresses (bytes, buf0): packed-line layout (0 conflicts).
  const int fr = lane & 15;
  const int qq = lane >> 4;
  unsigned adrA[4], adrB[4];
  {
    const unsigned base = (unsigned)(uintptr_t)(&L[0]);
#pragma unroll
    for (int mi = 0; mi < 4; ++mi) {
      const int R = wr * 64 + mi * 16 + fr;
      const int e = (R >> 1) * 64 + ((((R & 1) * 4 + qq) ^ ((R >> 1) & 7)) * 8);
      adrA[mi] = base + e * 2;
    }
#pragma unroll
    for (int ni = 0; ni < 4; ++ni) {
      const int R = wc * 64 + ni * 16 + fr;
      const int e = (R >> 1) * 64 + ((((R & 1) * 4 + qq) ^ ((R >> 1) & 7)) * 8);
      adrB[ni] = base + 8192 + e * 2;
    }
  }

  const f32x4 z = {0.f, 0.f, 0.f, 0.f};
  f32x4 acc[4][4];
#pragma unroll
  for (int i = 0; i < 4; ++i)
#pragma unroll
    for (int j = 0; j < 4; ++j) acc[i][j] = z;

  i32x4 Xa0, Xa1, Xa2, Xa3, Xb0, Xb1, Xb2, Xb3;
  i32x4 Ya0, Ya1, Ya2, Ya3, Yb0, Yb1, Yb2, Yb3;

#define READ_X(OFS) do { \
    DSREAD(Xb0, adrB[0], OFS); DSREAD(Xb1, adrB[1], OFS); \
    DSREAD(Xb2, adrB[2], OFS); DSREAD(Xb3, adrB[3], OFS); \
    DSREAD(Xa0, adrA[0], OFS); DSREAD(Xa1, adrA[1], OFS); \
    DSREAD(Xa2, adrA[2], OFS); DSREAD(Xa3, adrA[3], OFS); \
  } while (0)
#define READ_Y(OFS) do { \
    DSREAD(Yb0, adrB[0], OFS); DSREAD(Yb1, adrB[1], OFS); \
    DSREAD(Yb2, adrB[2], OFS); DSREAD(Yb3, adrB[3], OFS); \
    DSREAD(Ya0, adrA[0], OFS); DSREAD(Ya1, adrA[1], OFS); \
    DSREAD(Ya2, adrA[2], OFS); DSREAD(Ya3, adrA[3], OFS); \
  } while (0)

#define MFMA_ROW(a_, b0_, b1_, b2_, b3_, mi) do { \
    acc[mi][0] = __builtin_amdgcn_mfma_f32_16x16x32_bf16(BCAST(a_), BCAST(b0_), acc[mi][0], 0, 0, 0); \
    acc[mi][1] = __builtin_amdgcn_mfma_f32_16x16x32_bf16(BCAST(a_), BCAST(b1_), acc[mi][1], 0, 0, 0); \
    acc[mi][2] = __builtin_amdgcn_mfma_f32_16x16x32_bf16(BCAST(a_), BCAST(b2_), acc[mi][2], 0, 0, 0); \
    acc[mi][3] = __builtin_amdgcn_mfma_f32_16x16x32_bf16(BCAST(a_), BCAST(b3_), acc[mi][3], 0, 0, 0); \
  } while (0)

#define MFMA_X() do { \
    __builtin_amdgcn_s_setprio(1); \
    MFMA_ROW(Xa0, Xb0, Xb1, Xb2, Xb3, 0); \
    MFMA_ROW(Xa1, Xb0, Xb1, Xb2, Xb3, 1); \
    MFMA_ROW(Xa2, Xb0, Xb1, Xb2, Xb3, 2); \
    MFMA_ROW(Xa3, Xb0, Xb1, Xb2, Xb3, 3); \
    __builtin_amdgcn_s_setprio(0); \
  } while (0)
#define MFMA_Y() do { \
    __builtin_amdgcn_s_setprio(1); \
    MFMA_ROW(Ya0, Yb0, Yb1, Yb2, Yb3, 0); \
    MFMA_ROW(Ya1, Yb0, Yb1, Yb2, Yb3, 1); \
    MFMA_ROW(Ya2, Yb0, Yb1, Yb2, Yb3, 2); \
    MFMA_ROW(Ya3, Yb0, Yb1, Yb2, Yb3, 3); \
    __builtin_amdgcn_s_setprio(0); \
  } while (0)

  // Tile t (CUR=X even / Y odd):
  //  STAGE(t+2); vmcnt(4); SBAR           (stage t+1 visible; t+2 in flight)
  //  issue 8 asm ds_reads of buf[t+1] -> NXT
  //  MFMA(CUR)                            (no wait: CUR landed last tile)
  //  lgkmcnt(0)+sched_barrier             (NXT valid; waited UNDER the MFMAs)
  //  SBAR                                 (reads of buf[t] globally drained)
#define TILE_X(stgB, OFSRD, k0) do { \
    STAGE(stgB, k0); VMWAIT(4); SBAR(); SCHED(); \
    READ_Y(OFSRD); SCHED(); \
    MFMA_X(); \
    LGKM0(); \
    SBAR(); \
  } while (0)
#define TILE_Y(stgB, OFSRD, k0) do { \
    STAGE(stgB, k0); VMWAIT(4); SBAR(); SCHED(); \
    READ_X(OFSRD); SCHED(); \
    MFMA_Y(); \
    LGKM0(); \
    SBAR(); \
  } while (0)

  // prologue: stage tiles 0,1; wait tile 0; read tile-0 regs into X.
  STAGE(0, 0);
  STAGE(1, BK);
  VMWAIT(4);
  SBAR();
  SCHED();
  READ_X("0");
  LGKM0();

  // main loop: tiles 0..59 (staging 2..61). Buffers: t%3 -> 0/16384/32768.
#pragma unroll 1
  for (int s = 0; s < 10; ++s) {
    const int kb = (6 * s + 2) * BK;
    TILE_X(2, "16384", kb);            // t=6s+0: cur buf0, read buf1
    TILE_Y(0, "32768", kb + BK);       // t=6s+1: cur buf1, read buf2
    TILE_X(1, "0",     kb + 2 * BK);   // t=6s+2: cur buf2, read buf0
    TILE_Y(2, "16384", kb + 3 * BK);   // t=6s+3
    TILE_X(0, "32768", kb + 4 * BK);   // t=6s+4
    TILE_Y(1, "0",     kb + 5 * BK);   // t=6s+5
  }

  // tail: t=60 (cur buf0, stage 62->buf2), t=61 (cur buf1, stage 63->buf0).
  TILE_X(2, "16384", 62 * BK);         // t=60
  TILE_Y(0, "32768", 63 * BK);         // t=61
  // t=62 (cur=X from buf2): drain staging; read tile-63 (buf0) into Y.
  VMWAIT(0);
  SBAR();
  SCHED();
  READ_Y("0");
  SCHED();
  MFMA_X();
  LGKM0();
  MFMA_Y();                            // t=63

  // ---- epilogue: C/D layout col = lane&15, row = (lane>>4)*4 + r ----
  const int orow0 = bm * BM + wr * 64 + qq * 4;
  const int ocol0 = bn * BN + wc * 64 + fr;
#pragma unroll
  for (int ni = 0; ni < 4; ++ni) {
    const int col = ocol0 + ni * 16;
    const float bvv = bias[col];
#pragma unroll
    for (int mi = 0; mi < 4; ++mi) {
      const int row = orow0 + mi * 16;
#pragma unroll
      for (int r = 0; r < 4; ++r)
        C[(size_t)(row + r) * N_DIM + col] = acc[mi][ni][r] + bvv;
    }
  }
#undef TILE_X
#undef TILE_Y
#undef MFMA_X
#undef MFMA_Y
#undef MFMA_ROW
#undef READ_X
#undef READ_Y
#undef STAGE
}

// ---- safety fallback ----
__global__ __launch_bounds__(256) void gemm_f32_naive(
    const float* __restrict__ X, const float* __restrict__ W,
    const float* __restrict__ bias, float* __restrict__ C) {
  int o = blockIdx.x * 256 + threadIdx.x;
  if (o >= M_DIM * N_DIM) return;
  int m = o / N_DIM, n = o % N_DIM;
  const float* xr = X + (size_t)m * K_DIM;
  const float* wr = W + (size_t)n * K_DIM;
  float s = 0.f;
  for (int k = 0; k < K_DIM; ++k) s += xr[k] * wr[k];
  C[o] = s + bias[n];
}

extern "C" void kernel_launch(void* const* d_in, const int* in_sizes, int n_in,
                              void* d_out, int out_size, void* d_ws, size_t ws_size,
                              hipStream_t stream) {
  const float* x    = (const float*)d_in[0];
  const float* w    = (const float*)d_in[1];
  const float* bias = (const float*)d_in[2];
  float* out = (float*)d_out;

  const size_t x_elems = (size_t)M_DIM * K_DIM;
  const size_t w_elems = (size_t)N_DIM * K_DIM;
  const size_t need = (x_elems + w_elems) * sizeof(unsigned short);

  if (ws_size < need) {
    gemm_f32_naive<<<(M_DIM * N_DIM + 255) / 256, 256, 0, stream>>>(x, w, bias, out);
    return;
  }

  unsigned short* xb = (unsigned short*)d_ws;
  unsigned short* wb = xb + x_elems;

  const int xn8 = (int)(x_elems / 8);
  const int totn8 = (int)((x_elems + w_elems) / 8);
  cvt_both<<<(totn8 + 255) / 256, 256, 0, stream>>>(x, w, xb, xn8, totn8);

  // (2048/128) x (4096/128) = 512 blocks = 2/CU.
  gemm_asm<<<512, 256, 0, stream>>>(xb, wb, bias, out);
}

// Round 14
// 56.727 us; speedup vs baseline: 1.0423x; 1.0004x over previous
//
#include <hip/hip_runtime.h>
#include <hip/hip_bf16.h>

// x[4096,2048] f32, w[2048,2048] f32, bias[2048] f32, indices = permutation of
// K axis applied to BOTH operands -> cancels out of the einsum; unused.
#define M_DIM 4096
#define N_DIM 2048
#define K_DIM 2048

// Single-barrier all-counted pipeline: 128x128, 4 waves, 2 blocks/CU,
// BK=32, FOUR LDS buffers (64 KiB), stage distance 3, STAGE at tile END.
// Per tile: 1 s_barrier + vmcnt(4) + lgkmcnt(8). No drains in the loop.
#define BM 128
#define BN 128
#define BK 32
#define NT (K_DIM / BK)      // 64 K-tiles
#define BUF_EL 8192          // elems per buffer: A 4096 + B 4096 (16 KiB)

typedef __bf16 bf16x8 __attribute__((ext_vector_type(8)));
typedef float f32x4 __attribute__((ext_vector_type(4)));
typedef int   i32x4 __attribute__((ext_vector_type(4)));
typedef unsigned short u16x8 __attribute__((ext_vector_type(8)));

__device__ __forceinline__ unsigned short f32_to_bf16_rne(float f) {
  unsigned int u = __float_as_uint(f);
  u += 0x7fffu + ((u >> 16) & 1u);
  return (unsigned short)(u >> 16);
}

// ---- merged f32 -> bf16 conversion (row-major, verified) ----
__global__ __launch_bounds__(256) void cvt_both(
    const float* __restrict__ x, const float* __restrict__ w,
    unsigned short* __restrict__ out, int xn8, int totn8) {
  int i = blockIdx.x * 256 + threadIdx.x;
  if (i >= totn8) return;
  const float* src = (i < xn8) ? (x + (size_t)i * 8)
                               : (w + (size_t)(i - xn8) * 8);
  f32x4 a = reinterpret_cast<const f32x4*>(src)[0];
  f32x4 b = reinterpret_cast<const f32x4*>(src)[1];
  u16x8 o;
  o[0] = f32_to_bf16_rne(a[0]); o[1] = f32_to_bf16_rne(a[1]);
  o[2] = f32_to_bf16_rne(a[2]); o[3] = f32_to_bf16_rne(a[3]);
  o[4] = f32_to_bf16_rne(b[0]); o[5] = f32_to_bf16_rne(b[1]);
  o[6] = f32_to_bf16_rne(b[2]); o[7] = f32_to_bf16_rne(b[3]);
  reinterpret_cast<u16x8*>(out)[i] = o;
}

__device__ __forceinline__ void gload_lds16(const unsigned short* g, unsigned short* l) {
  __builtin_amdgcn_global_load_lds(
      (const __attribute__((address_space(1))) unsigned int*)g,
      (__attribute__((address_space(3))) unsigned int*)l, 16, 0, 0);
}

#define VMWAIT_(n) asm volatile("s_waitcnt vmcnt(" #n ")" ::: "memory")
#define VMWAIT(n) VMWAIT_(n)
#define LGKM_(n) asm volatile("s_waitcnt lgkmcnt(" #n ")" ::: "memory")
#define SBAR() __builtin_amdgcn_s_barrier()
#define SCHED() __builtin_amdgcn_sched_barrier(0)

// Opaque LDS read: buffer selected by 16-bit offset: literal.
#define DSREAD(dst, addr, OFS) \
  asm volatile("ds_read_b128 %0, %1 offset:" OFS : "=v"(dst) : "v"(addr))

#define BCAST(v) __builtin_bit_cast(bf16x8, v)

__global__ __launch_bounds__(256, 2) void gemm_1b(
    const unsigned short* __restrict__ A,   // [M][K] bf16 bits
    const unsigned short* __restrict__ B,   // [N][K] bf16 bits
    const float* __restrict__ bias,         // [N]
    float* __restrict__ C) {                // [M][N] f32
  __shared__ unsigned short L[4 * BUF_EL];  // 64 KiB: buf k at byte 16384*k

  const int tid  = threadIdx.x;   // 0..255
  const int lane = tid & 63;
  const int wave = tid >> 6;      // 0..3
  const int wr   = wave >> 1;     // 0..1 (M)
  const int wc   = wave & 1;      // 0..1 (N)

  // 2D XCD swizzle (verified: FETCH halved).
  const int orig = blockIdx.x;    // 0..511
  const int xcd  = orig & 7;
  const int idx  = orig >> 3;     // 0..63
  const int bm   = (xcd & 3) * 8 + (idx & 7);   // 0..31
  const int bn   = (xcd >> 2) * 8 + (idx >> 3); // 0..15

  // ---- staging source (inverse-permuted global addresses; rule 21) ----
  const int lid  = tid >> 3;
  const int uu   = (tid & 7) ^ (lid & 7);
  const int grow = 2 * lid + (uu >> 2);
  const int kc   = (uu & 3) * 8;
  const unsigned short* Ag[2];
  const unsigned short* Bg[2];
#pragma unroll
  for (int j = 0; j < 2; ++j) {
    Ag[j] = A + (size_t)(bm * BM + j * 64 + grow) * K_DIM + kc;
    Bg[j] = B + (size_t)(bn * BN + j * 64 + grow) * K_DIM + kc;
  }

  // dest within buf: A at elem 0, B at elem 4096. Linear (rule 21).
#define STAGE(bufLit, k0) do { \
    unsigned short* _da = &L[(bufLit) * BUF_EL + tid * 8]; \
    unsigned short* _db = &L[(bufLit) * BUF_EL + 4096 + tid * 8]; \
    gload_lds16(Ag[0] + (k0), _da); \
    gload_lds16(Ag[1] + (k0), _da + 2048); \
    gload_lds16(Bg[0] + (k0), _db); \
    gload_lds16(Bg[1] + (k0), _db + 2048); \
  } while (0)

  // ---- ds_read addresses (bytes, buf0): packed-line layout (0 conflicts).
  const int fr = lane & 15;
  const int qq = lane >> 4;
  unsigned adrA[4], adrB[4];
  {
    const unsigned base = (unsigned)(uintptr_t)(&L[0]);
#pragma unroll
    for (int mi = 0; mi < 4; ++mi) {
      const int R = wr * 64 + mi * 16 + fr;
      const int e = (R >> 1) * 64 + ((((R & 1) * 4 + qq) ^ ((R >> 1) & 7)) * 8);
      adrA[mi] = base + e * 2;
    }
#pragma unroll
    for (int ni = 0; ni < 4; ++ni) {
      const int R = wc * 64 + ni * 16 + fr;
      const int e = (R >> 1) * 64 + ((((R & 1) * 4 + qq) ^ ((R >> 1) & 7)) * 8);
      adrB[ni] = base + 8192 + e * 2;
    }
  }

  const f32x4 z = {0.f, 0.f, 0.f, 0.f};
  f32x4 acc[4][4];
#pragma unroll
  for (int i = 0; i < 4; ++i)
#pragma unroll
    for (int j = 0; j < 4; ++j) acc[i][j] = z;

  i32x4 Xa0, Xa1, Xa2, Xa3, Xb0, Xb1, Xb2, Xb3;
  i32x4 Ya0, Ya1, Ya2, Ya3, Yb0, Yb1, Yb2, Yb3;

#define READ_X(OFS) do { \
    DSREAD(Xb0, adrB[0], OFS); DSREAD(Xb1, adrB[1], OFS); \
    DSREAD(Xb2, adrB[2], OFS); DSREAD(Xb3, adrB[3], OFS); \
    DSREAD(Xa0, adrA[0], OFS); DSREAD(Xa1, adrA[1], OFS); \
    DSREAD(Xa2, adrA[2], OFS); DSREAD(Xa3, adrA[3], OFS); \
  } while (0)
#define READ_Y(OFS) do { \
    DSREAD(Yb0, adrB[0], OFS); DSREAD(Yb1, adrB[1], OFS); \
    DSREAD(Yb2, adrB[2], OFS); DSREAD(Yb3, adrB[3], OFS); \
    DSREAD(Ya0, adrA[0], OFS); DSREAD(Ya1, adrA[1], OFS); \
    DSREAD(Ya2, adrA[2], OFS); DSREAD(Ya3, adrA[3], OFS); \
  } while (0)

#define MFMA_ROW(a_, b0_, b1_, b2_, b3_, mi) do { \
    acc[mi][0] = __builtin_amdgcn_mfma_f32_16x16x32_bf16(BCAST(a_), BCAST(b0_), acc[mi][0], 0, 0, 0); \
    acc[mi][1] = __builtin_amdgcn_mfma_f32_16x16x32_bf16(BCAST(a_), BCAST(b1_), acc[mi][1], 0, 0, 0); \
    acc[mi][2] = __builtin_amdgcn_mfma_f32_16x16x32_bf16(BCAST(a_), BCAST(b2_), acc[mi][2], 0, 0, 0); \
    acc[mi][3] = __builtin_amdgcn_mfma_f32_16x16x32_bf16(BCAST(a_), BCAST(b3_), acc[mi][3], 0, 0, 0); \
  } while (0)

#define MFMA_X() do { \
    __builtin_amdgcn_s_setprio(1); \
    MFMA_ROW(Xa0, Xb0, Xb1, Xb2, Xb3, 0); \
    MFMA_ROW(Xa1, Xb0, Xb1, Xb2, Xb3, 1); \
    MFMA_ROW(Xa2, Xb0, Xb1, Xb2, Xb3, 2); \
    MFMA_ROW(Xa3, Xb0, Xb1, Xb2, Xb3, 3); \
    __builtin_amdgcn_s_setprio(0); \
  } while (0)
#define MFMA_Y() do { \
    __builtin_amdgcn_s_setprio(1); \
    MFMA_ROW(Ya0, Yb0, Yb1, Yb2, Yb3, 0); \
    MFMA_ROW(Ya1, Yb0, Yb1, Yb2, Yb3, 1); \
    MFMA_ROW(Ya2, Yb0, Yb1, Yb2, Yb3, 2); \
    MFMA_ROW(Ya3, Yb0, Yb1, Yb2, Yb3, 3); \
    __builtin_amdgcn_s_setprio(0); \
  } while (0)

  // Tile t (single barrier, all counted):
  //  VMWAIT(4): stage(t+1) landed (stage t+2, t+3 in flight, never drained)
  //  SBAR: (a) stage(t+1) visible to all waves; (b) WAR fence -- every
  //        wave's reads of buf[(t+3)%4] (tile t-1 set) retired at its own
  //        LGKM(8) in tile t-1, i.e. before this barrier.
  //  READ(next <- buf[(t+1)%4]): 8 asm ds_reads (fly across next barrier;
  //        their buffer is not re-staged until t+2 -- safe).
  //  LGKM(8): cur-set retired (issued last tile). sched_barrier: rule 18.
  //  MFMA(cur): zero waits.
  //  STAGE(buf[(t+3)%4], k=(t+3)*BK): 4 gloads, issued at tile END.
#define TILE_X(RDOFS, stgB, k0) do { \
    VMWAIT(4); SBAR(); SCHED(); \
    READ_Y(RDOFS); \
    LGKM_(8); SCHED(); \
    MFMA_X(); \
    STAGE(stgB, k0); \
  } while (0)
#define TILE_Y(RDOFS, stgB, k0) do { \
    VMWAIT(4); SBAR(); SCHED(); \
    READ_X(RDOFS); \
    LGKM_(8); SCHED(); \
    MFMA_Y(); \
    STAGE(stgB, k0); \
  } while (0)

  // prologue: stage tiles 0,1,2 (12 gloads); wait stage0; read tile-0 -> X.
  STAGE(0, 0);
  STAGE(1, BK);
  STAGE(2, 2 * BK);
  VMWAIT(8);
  SBAR();
  SCHED();
  READ_X("0");

  // main loop: tiles 0..59 (staging 3..62), unrolled by 4 for literals.
  // even tile -> MFMA X / read Y; odd -> MFMA Y / read X.
#pragma unroll 1
  for (int s = 0; s < 15; ++s) {
    const int kb = (4 * s + 3) * BK;
    TILE_X("16384", 3, kb);            // t=4s+0: read buf1, stage buf3
    TILE_Y("32768", 0, kb + BK);       // t=4s+1: read buf2, stage buf0
    TILE_X("49152", 1, kb + 2 * BK);   // t=4s+2: read buf3, stage buf1
    TILE_Y("0",     2, kb + 3 * BK);   // t=4s+3: read buf0, stage buf2
  }

  // tail: t=60 (stage 63), 61, 62, 63.
  TILE_X("16384", 3, 63 * BK);         // t=60: read 61<-buf1, stage 63->buf3
  // t=61: no staging left beyond 63.
  VMWAIT(4); SBAR(); SCHED();
  READ_X("32768");                     // read 62 <- buf2 (stage62 landed)
  LGKM_(8); SCHED();
  MFMA_Y();                            // tile 61
  // t=62: stage63 is the only outstanding vm load -> drain it.
  VMWAIT(0); SBAR(); SCHED();
  READ_Y("49152");                     // read 63 <- buf3
  LGKM_(8); SCHED();
  MFMA_X();                            // tile 62
  // t=63:
  LGKM_(0); SCHED();
  MFMA_Y();                            // tile 63

  // ---- epilogue: C/D layout col = lane&15, row = (lane>>4)*4 + r ----
  const int orow0 = bm * BM + wr * 64 + qq * 4;
  const int ocol0 = bn * BN + wc * 64 + fr;
#pragma unroll
  for (int ni = 0; ni < 4; ++ni) {
    const int col = ocol0 + ni * 16;
    const float bvv = bias[col];
#pragma unroll
    for (int mi = 0; mi < 4; ++mi) {
      const int row = orow0 + mi * 16;
#pragma unroll
      for (int r = 0; r < 4; ++r)
        C[(size_t)(row + r) * N_DIM + col] = acc[mi][ni][r] + bvv;
    }
  }
#undef TILE_X
#undef TILE_Y
#undef MFMA_X
#undef MFMA_Y
#undef MFMA_ROW
#undef READ_X
#undef READ_Y
#undef STAGE
}

// ---- safety fallback ----
__global__ __launch_bounds__(256) void gemm_f32_naive(
    const float* __restrict__ X, const float* __restrict__ W,
    const float* __restrict__ bias, float* __restrict__ C) {
  int o = blockIdx.x * 256 + threadIdx.x;
  if (o >= M_DIM * N_DIM) return;
  int m = o / N_DIM, n = o % N_DIM;
  const float* xr = X + (size_t)m * K_DIM;
  const float* wr = W + (size_t)n * K_DIM;
  float s = 0.f;
  for (int k = 0; k < K_DIM; ++k) s += xr[k] * wr[k];
  C[o] = s + bias[n];
}

extern "C" void kernel_launch(void* const* d_in, const int* in_sizes, int n_in,
                              void* d_out, int out_size, void* d_ws, size_t ws_size,
                              hipStream_t stream) {
  const float* x    = (const float*)d_in[0];
  const float* w    = (const float*)d_in[1];
  const float* bias = (const float*)d_in[2];
  float* out = (float*)d_out;

  const size_t x_elems = (size_t)M_DIM * K_DIM;
  const size_t w_elems = (size_t)N_DIM * K_DIM;
  const size_t need = (x_elems + w_elems) * sizeof(unsigned short);

  if (ws_size < need) {
    gemm_f32_naive<<<(M_DIM * N_DIM + 255) / 256, 256, 0, stream>>>(x, w, bias, out);
    return;
  }

  unsigned short* xb = (unsigned short*)d_ws;
  unsigned short* wb = xb + x_elems;

  const int xn8 = (int)(x_elems / 8);
  const int totn8 = (int)((x_elems + w_elems) / 8);
  cvt_both<<<(totn8 + 255) / 256, 256, 0, stream>>>(x, w, xb, xn8, totn8);

  // (2048/128) x (4096/128) = 512 blocks = 2/CU.
  gemm_1b<<<512, 256, 0, stream>>>(xb, wb, bias, out);
}